// Round 8
// baseline (1993.682 us; speedup 1.0000x reference)
//
#include <hip/hip_runtime.h>
#include <stdint.h>

// BitNet MLP, int8-MFMA. GEMM core: 4 waves (1/SIMD), per-wave 128x128 tile,
// acc 8x8 f32x4 in AGPR, double-buffered frag regs so ds_reads of tile t+1
// drain under the 64-MFMA burst of tile t. 4-deep LDS ring, counted vmcnt,
// raw barriers, verified-conflict-free swizzle (r6/r7: SQ_LDS_BANK_CONFLICT=0).
// All integer dot products exact; only fp32 scale factors round.

typedef int i32x4 __attribute__((ext_vector_type(4)));
typedef short s16x8 __attribute__((ext_vector_type(8)));

#define HD 4096
#define ID 11008
#define MD 4096          // B*S tokens
#define WN 45088768      // 11008*4096 per weight
#define N1 22016         // gate|up fused output width
#define QEPS 1e-5f
#define SQRT7 2.6457513110645907f

#define MFMA_I8(a, b, c) __builtin_amdgcn_mfma_i32_16x16x64_i8(a, b, c, 0, 0, 0)

__device__ __forceinline__ void gload_lds16(const char* g, char* l) {
  __builtin_amdgcn_global_load_lds((const __attribute__((address_space(1))) void*)g,
                                   (__attribute__((address_space(3))) void*)l, 16, 0, 0);
}

// ---- stage a 256row x 64B half-tile (16KB) with 256 threads, swizzled ------
// Thread t covers LDS bytes t*16 (+4096/round): row=t>>2, slot=t&3.
// Image swizzle slot ^= (row>>1)&3 -> source slot = (t&3)^((t>>3)&3).
// Rounds add 64 rows: (64>>1)&3 == 0, swizzle invariant. Verified 0-conflict.
__device__ __forceinline__ void stage64q(const char* __restrict__ g, int ldk,
                                         char* lds, int t) {
  int r = t >> 2, sl = (t & 3) ^ ((t >> 3) & 3);
  const char* gp = g + (size_t)r * ldk + (sl << 4);
  char* lp = lds + t * 16;
#pragma unroll
  for (int i = 0; i < 4; ++i) {
    gload_lds16(gp, lp);
    gp += (size_t)64 * ldk;
    lp += 4096;
  }
}

__device__ __forceinline__ void read_frags(const char* __restrict__ slot,
                                           int wr, int wc, int lr, int sw4,
                                           i32x4 (&A)[8], i32x4 (&B)[8]) {
  const char* Ab = slot;            // 256x64 A half
  const char* Bb = slot + 16384;    // 256x64 B half
#pragma unroll
  for (int i = 0; i < 8; ++i)
    A[i] = *(const i32x4*)(Ab + (wr + i * 16 + lr) * 64 + sw4);
#pragma unroll
  for (int i = 0; i < 8; ++i)
    B[i] = *(const i32x4*)(Bb + (wc + i * 16 + lr) * 64 + sw4);
}

__device__ __forceinline__ void mfma_burst(const i32x4 (&A)[8], const i32x4 (&B)[8],
                                           i32x4 (&acc)[8][8]) {
  __builtin_amdgcn_s_setprio(1);
#pragma unroll
  for (int n = 0; n < 8; ++n)
#pragma unroll
    for (int m = 0; m < 8; ++m)
      acc[m][n] = MFMA_I8(A[m], B[n], acc[m][n]);
  __builtin_amdgcn_s_setprio(0);
}

// ---- 256x256 x K core. nt must be even (>=4). -------------------------------
__device__ __forceinline__ void gemm_core(const char* __restrict__ ga,
                                          const char* __restrict__ gb,
                                          int ldk, int nt, char* lds,
                                          i32x4 (&acc)[8][8], int w, int l) {
  const int t256 = w * 64 + l;
  const int wr = (w >> 1) * 128, wc = (w & 1) * 128;
  const int lr = l & 15;
  const int sw4 = (((l >> 4) ^ ((l >> 1) & 3)) << 4);
  i32x4 A0[8], B0[8], A1[8], B1[8];
  // prologue: stage tiles 0,1,2 (8 gloads/thread each)
#pragma unroll
  for (int pt = 0; pt < 3; ++pt) {
    stage64q(ga + (size_t)pt * 64, ldk, lds + pt * 32768, t256);
    stage64q(gb + (size_t)pt * 64, ldk, lds + pt * 32768 + 16384, t256);
  }
  asm volatile("s_waitcnt vmcnt(16)" ::: "memory");  // tile0 landed
  __builtin_amdgcn_s_barrier();
  read_frags(lds, wr, wc, lr, sw4, A0, B0);
  for (int t = 0; t < nt; t += 2) {
    {  // even: compute tile t (A0/B0), read frags t+1 -> A1/B1
      if (t + 2 < nt) asm volatile("s_waitcnt vmcnt(8)" ::: "memory");
      else            asm volatile("s_waitcnt vmcnt(0)" ::: "memory");
      __builtin_amdgcn_s_barrier();
      if (t + 3 < nt) {
        char* buf = lds + ((t + 3) & 3) * 32768;
        stage64q(ga + (size_t)(t + 3) * 64, ldk, buf, t256);
        stage64q(gb + (size_t)(t + 3) * 64, ldk, buf + 16384, t256);
      }
      read_frags(lds + ((t + 1) & 3) * 32768, wr, wc, lr, sw4, A1, B1);
      mfma_burst(A0, B0, acc);
    }
    {  // odd: compute tile t+1 (A1/B1), read frags t+2 -> A0/B0
      int u = t + 1;
      if (u + 1 < nt) {
        if (u + 2 < nt) asm volatile("s_waitcnt vmcnt(8)" ::: "memory");
        else            asm volatile("s_waitcnt vmcnt(0)" ::: "memory");
        __builtin_amdgcn_s_barrier();
        if (u + 3 < nt) {
          char* buf = lds + ((u + 3) & 3) * 32768;
          stage64q(ga + (size_t)(u + 3) * 64, ldk, buf, t256);
          stage64q(gb + (size_t)(u + 3) * 64, ldk, buf + 16384, t256);
        }
        read_frags(lds + ((u + 1) & 3) * 32768, wr, wc, lr, sw4, A0, B0);
      }
      mfma_burst(A1, B1, acc);
    }
  }
}

// ---------------- GEMM1: xq x [wgq;wuq] -> C i16 ----------------------------
__global__ __launch_bounds__(256, 1) void gemm1_kernel(
    const char* __restrict__ A, const char* __restrict__ B, short* __restrict__ C) {
  __shared__ __align__(16) char lds[131072];
  int t = threadIdx.x, w = t >> 6, l = t & 63;
  // bn-major XCD mapping: on-XCD neighbors share B panels (1376 = 8*172)
  int wgid = ((int)blockIdx.x & 7) * 172 + ((int)blockIdx.x >> 3);
  int bm = wgid & 15, bn = wgid >> 4;  // bm in [0,16), bn in [0,86)
  i32x4 acc[8][8] = {};
  gemm_core(A + (size_t)bm * 256 * HD, B + (size_t)bn * 256 * HD, HD, HD / 64,
            lds, acc, w, l);
  int wr = (w >> 1) * 128, wc = (w & 1) * 128, lr = l & 15, lj = (l >> 4) * 4;
#pragma unroll
  for (int mi = 0; mi < 8; ++mi) {
    int row = bm * 256 + wr + mi * 16 + lj;
#pragma unroll
    for (int ni = 0; ni < 8; ++ni) {
      int col = bn * 256 + wc + ni * 16 + lr;
#pragma unroll
      for (int j = 0; j < 4; ++j) {
        int v = acc[mi][ni][j];
        v = v < -32768 ? -32768 : (v > 32767 ? 32767 : v);  // never triggers (|acc|<~2k)
        C[(size_t)(row + j) * N1 + col] = (short)v;
      }
    }
  }
}

// ---------------- GEMM2: hq x wdq, fused scales -> f32 ----------------------
__global__ __launch_bounds__(256, 1) void gemm_down_kernel(
    const char* __restrict__ A, const char* __restrict__ B, float* __restrict__ out,
    const float* __restrict__ gammaF, const double* __restrict__ sums,
    const float* __restrict__ sd) {
  __shared__ __align__(16) char lds[131072];
  int t = threadIdx.x, w = t >> 6, l = t & 63;
  int wgid = ((int)blockIdx.x & 7) * 32 + ((int)blockIdx.x >> 3);  // 256 = 8*32
  int bm = wgid & 15, bn = wgid >> 4;
  i32x4 acc[8][8] = {};
  gemm_core(A + (size_t)bm * 256 * ID, B + (size_t)bn * 256 * ID, ID, ID / 64,
            lds, acc, w, l);
  float wdm = (float)(sums[2] * (1.0 / (double)WN)) * sd[0] * (1.f / 127.f);
  int wr = (w >> 1) * 128, wc = (w & 1) * 128, lr = l & 15, lj = (l >> 4) * 4;
#pragma unroll
  for (int mi = 0; mi < 8; ++mi) {
    int row = bm * 256 + wr + mi * 16 + lj;
    float sa[4];
#pragma unroll
    for (int j = 0; j < 4; ++j) sa[j] = gammaF[row + j] * wdm;
#pragma unroll
    for (int ni = 0; ni < 8; ++ni) {
      int col = bn * 256 + wc + ni * 16 + lr;
#pragma unroll
      for (int j = 0; j < 4; ++j)
        out[(size_t)(row + j) * HD + col] = (float)acc[mi][ni][j] * sa[j];
    }
  }
}

// ---------------- helpers ----------------------------------------------------
__device__ __forceinline__ int pack4div(float4 v, float mul, float den, float lo, float hi) {
  int a = (int)fminf(fmaxf(rintf((v.x * mul) / den), lo), hi);
  int b = (int)fminf(fmaxf(rintf((v.y * mul) / den), lo), hi);
  int c = (int)fminf(fmaxf(rintf((v.z * mul) / den), lo), hi);
  int d = (int)fminf(fmaxf(rintf((v.w * mul) / den), lo), hi);
  return (a & 255) | ((b & 255) << 8) | ((c & 255) << 16) | ((d & 255) << 24);
}

// ---------------- absmean reductions (double atomics) -----------------------
__global__ __launch_bounds__(256) void abssum_kernel(const float4* __restrict__ w,
                                                     int n8, double* __restrict__ out) {
  float s = 0.f;
  int stride = gridDim.x * blockDim.x;
  for (int i = blockIdx.x * blockDim.x + threadIdx.x; i < n8; i += stride) {
    float4 v0 = w[i * 2], v1 = w[i * 2 + 1];
    s += fabsf(v0.x) + fabsf(v0.y) + fabsf(v0.z) + fabsf(v0.w);
    s += fabsf(v1.x) + fabsf(v1.y) + fabsf(v1.z) + fabsf(v1.w);
  }
#pragma unroll
  for (int off = 32; off > 0; off >>= 1) s += __shfl_down(s, off);
  __shared__ float red[4];
  int l = threadIdx.x & 63, wv = threadIdx.x >> 6;
  if (l == 0) red[wv] = s;
  __syncthreads();
  if (threadIdx.x == 0) {
    double tt = (double)red[0] + (double)red[1] + (double)red[2] + (double)red[3];
    atomicAdd(out, tt);
  }
}

// ---------------- per-row beta + int4 quant of x -> i8 ----------------------
__global__ __launch_bounds__(256) void quantx_kernel(const float* __restrict__ x,
                                                     char* __restrict__ xq,
                                                     float* __restrict__ scale_x) {
  int row = blockIdx.x;
  const float4* xr = (const float4*)(x + (size_t)row * HD);
  int t = threadIdx.x;
  float4 v[4];
  float s = 0.f;
#pragma unroll
  for (int k = 0; k < 4; ++k) {
    v[k] = xr[t + k * 256];
    s += fabsf(v[k].x) + fabsf(v[k].y) + fabsf(v[k].z) + fabsf(v[k].w);
  }
#pragma unroll
  for (int off = 32; off > 0; off >>= 1) s += __shfl_down(s, off);
  __shared__ float red[4];
  int l = t & 63, wv = t >> 6;
  if (l == 0) red[wv] = s;
  __syncthreads();
  float beta = (red[0] + red[1] + red[2] + red[3]) * (1.f / (float)HD);
  if (t == 0) scale_x[row] = (beta * SQRT7) / SQRT7;  // ref dequant scale
  float den = beta + QEPS;
  int* qr = (int*)(xq + (size_t)row * HD);
#pragma unroll
  for (int k = 0; k < 4; ++k)
    qr[t + k * 256] = pack4div(v[k], SQRT7, den, -8.f, 7.f);
}

// ---------------- ternary quant of a weight -> i8 {-1,0,1} ------------------
__global__ __launch_bounds__(256) void quantw_kernel(const float4* __restrict__ w,
                                                     int4* __restrict__ wq,
                                                     const double* __restrict__ sum) {
  float mean = (float)(*sum * (1.0 / (double)WN));
  float den = mean + QEPS;
  int n16 = WN / 16;
  int stride = gridDim.x * blockDim.x;
  for (int i = blockIdx.x * blockDim.x + threadIdx.x; i < n16; i += stride) {
    float4 v0 = w[i * 4 + 0], v1 = w[i * 4 + 1], v2 = w[i * 4 + 2], v3 = w[i * 4 + 3];
    int4 o;
    o.x = pack4div(v0, 1.f, den, -1.f, 1.f);
    o.y = pack4div(v1, 1.f, den, -1.f, 1.f);
    o.z = pack4div(v2, 1.f, den, -1.f, 1.f);
    o.w = pack4div(v3, 1.f, den, -1.f, 1.f);
    wq[i] = o;
  }
}

// -------- combine: relu^2*up, per-row gamma, int8 quant (one block per row) --
__global__ __launch_bounds__(256) void combine_kernel(
    const short* __restrict__ C, const float* __restrict__ scale_x,
    const double* __restrict__ sums, const float* __restrict__ sg,
    const float* __restrict__ su, float* __restrict__ gammaF,
    char* __restrict__ hq) {
  int row = blockIdx.x, t = threadIdx.x;
  float gm = (float)(sums[0] * (1.0 / (double)WN)) * sg[0];
  float um = (float)(sums[1] * (1.0 / (double)WN)) * su[0];
  float sx = scale_x[row];
  float sxg = sx * gm, sxu = sx * um;
  const s16x8* g8 = (const s16x8*)(C + (size_t)row * N1);
  const s16x8* u8 = (const s16x8*)(C + (size_t)row * N1 + ID);
  float hv[6][8];
  float m = 0.f;
#pragma unroll
  for (int k = 0; k < 6; ++k) {
    int c = t + k * 256;
    if (c < ID / 8) {
      s16x8 gi = __builtin_nontemporal_load(&g8[c]);
      s16x8 ui = __builtin_nontemporal_load(&u8[c]);
#pragma unroll
      for (int e = 0; e < 8; ++e) {
        float rg = fmaxf((float)gi[e] * sxg, 0.f);
        hv[k][e] = ((float)ui[e] * sxu) * (rg * rg);
        m = fmaxf(m, fabsf(hv[k][e]));
      }
    }
  }
#pragma unroll
  for (int off = 32; off > 0; off >>= 1) m = fmaxf(m, __shfl_xor(m, off));
  __shared__ float red[4];
  if ((t & 63) == 0) red[t >> 6] = m;
  __syncthreads();
  float gamma = fmaxf(fmaxf(red[0], red[1]), fmaxf(red[2], red[3]));
  if (t == 0) gammaF[row] = gamma;
  float den = gamma + QEPS;
  int2* hr = (int2*)(hq + (size_t)row * ID);
#pragma unroll
  for (int k = 0; k < 6; ++k) {
    int c = t + k * 256;
    if (c < ID / 8) {
      int2 o;
      o.x = pack4div(make_float4(hv[k][0], hv[k][1], hv[k][2], hv[k][3]), 127.f, den, -128.f, 127.f);
      o.y = pack4div(make_float4(hv[k][4], hv[k][5], hv[k][6], hv[k][7]), 127.f, den, -128.f, 127.f);
      hr[c] = o;
    }
  }
}

extern "C" void kernel_launch(void* const* d_in, const int* in_sizes, int n_in,
                              void* d_out, int out_size, void* d_ws, size_t ws_size,
                              hipStream_t stream) {
  (void)in_sizes; (void)n_in; (void)out_size; (void)ws_size;
  const float* x = (const float*)d_in[0];
  const float* w_gate = (const float*)d_in[1];
  const float* w_up = (const float*)d_in[2];
  const float* w_down = (const float*)d_in[3];
  const float* s_gate = (const float*)d_in[4];
  const float* s_up = (const float*)d_in[5];
  const float* s_down = (const float*)d_in[6];
  float* out = (float*)d_out;

  // ws layout (bytes):
  char* p = (char*)d_ws;
  double* sums = (double*)p;                        // 3 doubles
  float* gammaF = (float*)(p + 256);                // 4096 f32
  float* scale_x = (float*)(p + 256 + 16384);       // 4096 f32 -> head ends 33024
  char* xq = p + 33024;                             // 16,777,216
  char* wgq = xq + 16777216UL;                      // 45,088,768 (wuq contiguous after!)
  char* wuq = wgq + (size_t)WN;                     // => [wgq;wuq] = 22016 x 4096 i8
  char* wdq = wuq + (size_t)WN;
  short* C16 = (short*)(wdq + (size_t)WN);          // 180,355,072 (4096 x 22016 i16)
  char* hq = (char*)C16 + 180355072UL;              // 45,088,768  (~378 MB total)

  (void)hipMemsetAsync(p, 0, 256, stream);  // sums

  // interleave per weight so quantw's re-read hits L3 (each weight f32 = 180MB)
  abssum_kernel<<<2048, 256, 0, stream>>>((const float4*)w_gate, WN / 8, sums + 0);
  quantw_kernel<<<2048, 256, 0, stream>>>((const float4*)w_gate, (int4*)wgq, sums + 0);
  abssum_kernel<<<2048, 256, 0, stream>>>((const float4*)w_up, WN / 8, sums + 1);
  quantw_kernel<<<2048, 256, 0, stream>>>((const float4*)w_up, (int4*)wuq, sums + 1);
  abssum_kernel<<<2048, 256, 0, stream>>>((const float4*)w_down, WN / 8, sums + 2);
  quantw_kernel<<<2048, 256, 0, stream>>>((const float4*)w_down, (int4*)wdq, sums + 2);

  quantx_kernel<<<MD, 256, 0, stream>>>(x, xq, scale_x);

  // fused gate|up: M=4096 (16 bm) x N=22016 (86 bn) -> 1376 blocks (= 8*172)
  gemm1_kernel<<<1376, 256, 0, stream>>>(xq, wgq, C16);

  combine_kernel<<<MD, 256, 0, stream>>>(C16, scale_x, sums, s_gate, s_up, gammaF, hq);

  // down: M=4096 x N=4096 -> 256 blocks (= 8*32), K=11008 (172 BK=64 tiles)
  gemm_down_kernel<<<256, 256, 0, stream>>>(hq, wdq, out, gammaF, sums, s_down);
}

// Round 10
// 1170.662 us; speedup vs baseline: 1.7030x; 1.7030x over previous
//
#include <hip/hip_runtime.h>
#include <stdint.h>

// BitNet MLP, int8-MFMA. GEMM core v3b: 8 waves, per-wave 128x64 tile,
// A staged via global_load_lds into a 4-deep 16KB LDS ring (swizzled,
// verified 0 bank conflicts r6/r7); B loaded global->VGPR directly
// (L2-resident panels, bn-major XCD swizzle), double-buffered 2 tiles ahead.
// Counted vmcnt(6) = exactly {stage(t+1..t+2) + B(t+1)} younger ops.
// r9 fixes: stageA stages BOTH 128-row halves (was half -> garbage);
// launch_bounds (512,2) not (512,4) (128-VGPR cap would spill acc).
// All integer dot products exact; only fp32 scale factors round.

typedef int i32x4 __attribute__((ext_vector_type(4)));
typedef short s16x8 __attribute__((ext_vector_type(8)));

#define HD 4096
#define ID 11008
#define MD 4096          // B*S tokens
#define WN 45088768      // 11008*4096 per weight
#define N1 22016         // gate|up fused output width
#define QEPS 1e-5f
#define SQRT7 2.6457513110645907f

#define MFMA_I8(a, b, c) __builtin_amdgcn_mfma_i32_16x16x64_i8(a, b, c, 0, 0, 0)

__device__ __forceinline__ void gload_lds16(const char* g, char* l) {
  __builtin_amdgcn_global_load_lds((const __attribute__((address_space(1))) void*)g,
                                   (__attribute__((address_space(3))) void*)l, 16, 0, 0);
}

// ---- stage a 256row x 64B A-tile (16KB) with 512 threads, swizzled image ----
// Thread t covers LDS bytes t*16 and t*16+8192 (rows r and r+128).
// Image: lds[row][slot] = g[row][slot ^ ((row>>1)&3)]; source slot =
// (t&3)^((t>>3)&3), invariant under row+=128. SQ_LDS_BANK_CONFLICT==0 (r6/r7).
__device__ __forceinline__ void stageA(const char* __restrict__ g, int ldk,
                                       char* lds, int t512) {
  int r = t512 >> 2, sl = (t512 & 3) ^ ((t512 >> 3) & 3);
  const char* gp = g + (size_t)r * ldk + (sl << 4);
  gload_lds16(gp, lds + t512 * 16);
  gload_lds16(gp + (size_t)128 * ldk, lds + t512 * 16 + 8192);
}

__device__ __forceinline__ void loadB(const char* __restrict__ gb, int ldk,
                                      int tile, int wc, int lr, int khi,
                                      i32x4 (&bq)[4]) {
  const char* bp = gb + (size_t)tile * 64 + khi;
#pragma unroll
  for (int ni = 0; ni < 4; ++ni)
    bq[ni] = *(const i32x4*)(bp + (size_t)(wc + ni * 16 + lr) * ldk);
}

// ---- one K-tile iteration (BK=64). bq passed by name (static indexing). ----
__device__ __forceinline__ void gemm_iter(const char* __restrict__ ga,
                                          const char* __restrict__ gb,
                                          int ldk, int nt, char* lds, int t,
                                          i32x4 (&bq)[4], i32x4 (&acc)[8][4],
                                          int t512, int wr, int wc, int lr,
                                          int sw4, int khi) {
  // entry outstanding (issue order): stage(t+1)[2] B(t)[4] stage(t+2)[2] B(t+1)[4]
  // vmcnt(6) retires stage(t+1)+B(t) -> stage(t) & B(t) both complete.
  if (t + 2 < nt)      asm volatile("s_waitcnt vmcnt(6)" ::: "memory");
  else if (t + 1 < nt) asm volatile("s_waitcnt vmcnt(4)" ::: "memory");
  else                 asm volatile("s_waitcnt vmcnt(0)" ::: "memory");
  __builtin_amdgcn_s_barrier();
  if (t + 3 < nt)  // slot (t+3)&3 == (t-1)&3: all t-1 reads done before this barrier
    stageA(ga + (size_t)(t + 3) * 64, ldk, lds + ((t + 3) & 3) * 16384, t512);
  const char* Ab = lds + (t & 3) * 16384;
  i32x4 af[8];
#pragma unroll
  for (int mi = 0; mi < 8; ++mi)
    af[mi] = *(const i32x4*)(Ab + (wr + mi * 16 + lr) * 64 + sw4);
  __builtin_amdgcn_s_setprio(1);
#pragma unroll
  for (int ni = 0; ni < 4; ++ni)
#pragma unroll
    for (int mi = 0; mi < 8; ++mi)
      acc[mi][ni] = MFMA_I8(af[mi], bq[ni], acc[mi][ni]);
  __builtin_amdgcn_s_setprio(0);
  if (t + 2 < nt)  // refill same parity set; WAR ordered after MFMAs by reg dep
    loadB(gb, ldk, t + 2, wc, lr, khi, bq);
}

// ---- 256x256 x K core. nt even, >= 4. --------------------------------------
__device__ __forceinline__ void gemm_core(const char* __restrict__ ga,
                                          const char* __restrict__ gb,
                                          int ldk, int nt, char* lds,
                                          i32x4 (&acc)[8][4], int w, int l) {
  const int t512 = w * 64 + l;
  const int wr = (w >> 2) * 128, wc = (w & 3) * 64;
  const int lr = l & 15, khi = (l >> 4) * 16;
  const int sw4 = (((l >> 4) ^ ((l >> 1) & 3)) << 4);
  i32x4 bqE[4], bqO[4];
  // prologue (order matters for vmcnt math): A0, A1, B0, A2, B1
  stageA(ga, ldk, lds, t512);
  stageA(ga + 64, ldk, lds + 16384, t512);
  loadB(gb, ldk, 0, wc, lr, khi, bqE);
  stageA(ga + 128, ldk, lds + 32768, t512);
  loadB(gb, ldk, 1, wc, lr, khi, bqO);
  for (int t = 0; t < nt; t += 2) {
    gemm_iter(ga, gb, ldk, nt, lds, t,     bqE, acc, t512, wr, wc, lr, sw4, khi);
    gemm_iter(ga, gb, ldk, nt, lds, t + 1, bqO, acc, t512, wr, wc, lr, sw4, khi);
  }
}

// ---------------- GEMM1: xq x [wgq;wuq] -> C i16 ----------------------------
__global__ __launch_bounds__(512, 2) void gemm1_kernel(
    const char* __restrict__ A, const char* __restrict__ B, short* __restrict__ C) {
  __shared__ __align__(16) char lds[65536];
  int t = threadIdx.x, w = t >> 6, l = t & 63;
  // bn-major XCD mapping: on-XCD neighbors share B panels (1376 = 8*172)
  int wgid = ((int)blockIdx.x & 7) * 172 + ((int)blockIdx.x >> 3);
  int bm = wgid & 15, bn = wgid >> 4;  // bm in [0,16), bn in [0,86)
  i32x4 acc[8][4] = {};
  gemm_core(A + (size_t)bm * 256 * HD, B + (size_t)bn * 256 * HD, HD, HD / 64,
            lds, acc, w, l);
  int wr = (w >> 2) * 128, wc = (w & 3) * 64, lr = l & 15, lj = (l >> 4) * 4;
#pragma unroll
  for (int mi = 0; mi < 8; ++mi) {
    int row = bm * 256 + wr + mi * 16 + lj;
#pragma unroll
    for (int ni = 0; ni < 4; ++ni) {
      int col = bn * 256 + wc + ni * 16 + lr;
#pragma unroll
      for (int j = 0; j < 4; ++j) {
        int v = acc[mi][ni][j];
        v = v < -32768 ? -32768 : (v > 32767 ? 32767 : v);  // never triggers (|acc|<~2k)
        C[(size_t)(row + j) * N1 + col] = (short)v;
      }
    }
  }
}

// ---------------- GEMM2: hq x wdq, fused scales -> f32 ----------------------
__global__ __launch_bounds__(512, 2) void gemm_down_kernel(
    const char* __restrict__ A, const char* __restrict__ B, float* __restrict__ out,
    const float* __restrict__ gammaF, const double* __restrict__ sums,
    const float* __restrict__ sd) {
  __shared__ __align__(16) char lds[65536];
  int t = threadIdx.x, w = t >> 6, l = t & 63;
  int wgid = ((int)blockIdx.x & 7) * 32 + ((int)blockIdx.x >> 3);  // 256 = 8*32
  int bm = wgid & 15, bn = wgid >> 4;
  i32x4 acc[8][4] = {};
  gemm_core(A + (size_t)bm * 256 * ID, B + (size_t)bn * 256 * ID, ID, ID / 64,
            lds, acc, w, l);
  float wdm = (float)(sums[2] * (1.0 / (double)WN)) * sd[0] * (1.f / 127.f);
  int wr = (w >> 2) * 128, wc = (w & 3) * 64, lr = l & 15, lj = (l >> 4) * 4;
#pragma unroll
  for (int mi = 0; mi < 8; ++mi) {
    int row = bm * 256 + wr + mi * 16 + lj;
    float sa[4];
#pragma unroll
    for (int j = 0; j < 4; ++j) sa[j] = gammaF[row + j] * wdm;
#pragma unroll
    for (int ni = 0; ni < 4; ++ni) {
      int col = bn * 256 + wc + ni * 16 + lr;
#pragma unroll
      for (int j = 0; j < 4; ++j)
        out[(size_t)(row + j) * HD + col] = (float)acc[mi][ni][j] * sa[j];
    }
  }
}

// ---------------- helpers ----------------------------------------------------
__device__ __forceinline__ int pack4div(float4 v, float mul, float den, float lo, float hi) {
  int a = (int)fminf(fmaxf(rintf((v.x * mul) / den), lo), hi);
  int b = (int)fminf(fmaxf(rintf((v.y * mul) / den), lo), hi);
  int c = (int)fminf(fmaxf(rintf((v.z * mul) / den), lo), hi);
  int d = (int)fminf(fmaxf(rintf((v.w * mul) / den), lo), hi);
  return (a & 255) | ((b & 255) << 8) | ((c & 255) << 16) | ((d & 255) << 24);
}

// ---------------- absmean reductions (double atomics) -----------------------
__global__ __launch_bounds__(256) void abssum_kernel(const float4* __restrict__ w,
                                                     int n8, double* __restrict__ out) {
  float s = 0.f;
  int stride = gridDim.x * blockDim.x;
  for (int i = blockIdx.x * blockDim.x + threadIdx.x; i < n8; i += stride) {
    float4 v0 = w[i * 2], v1 = w[i * 2 + 1];
    s += fabsf(v0.x) + fabsf(v0.y) + fabsf(v0.z) + fabsf(v0.w);
    s += fabsf(v1.x) + fabsf(v1.y) + fabsf(v1.z) + fabsf(v1.w);
  }
#pragma unroll
  for (int off = 32; off > 0; off >>= 1) s += __shfl_down(s, off);
  __shared__ float red[4];
  int l = threadIdx.x & 63, wv = threadIdx.x >> 6;
  if (l == 0) red[wv] = s;
  __syncthreads();
  if (threadIdx.x == 0) {
    double tt = (double)red[0] + (double)red[1] + (double)red[2] + (double)red[3];
    atomicAdd(out, tt);
  }
}

// ---------------- per-row beta + int4 quant of x -> i8 ----------------------
__global__ __launch_bounds__(256) void quantx_kernel(const float* __restrict__ x,
                                                     char* __restrict__ xq,
                                                     float* __restrict__ scale_x) {
  int row = blockIdx.x;
  const float4* xr = (const float4*)(x + (size_t)row * HD);
  int t = threadIdx.x;
  float4 v[4];
  float s = 0.f;
#pragma unroll
  for (int k = 0; k < 4; ++k) {
    v[k] = xr[t + k * 256];
    s += fabsf(v[k].x) + fabsf(v[k].y) + fabsf(v[k].z) + fabsf(v[k].w);
  }
#pragma unroll
  for (int off = 32; off > 0; off >>= 1) s += __shfl_down(s, off);
  __shared__ float red[4];
  int l = t & 63, wv = t >> 6;
  if (l == 0) red[wv] = s;
  __syncthreads();
  float beta = (red[0] + red[1] + red[2] + red[3]) * (1.f / (float)HD);
  if (t == 0) scale_x[row] = (beta * SQRT7) / SQRT7;  // ref dequant scale
  float den = beta + QEPS;
  int* qr = (int*)(xq + (size_t)row * HD);
#pragma unroll
  for (int k = 0; k < 4; ++k)
    qr[t + k * 256] = pack4div(v[k], SQRT7, den, -8.f, 7.f);
}

// ---------------- ternary quant of a weight -> i8 {-1,0,1} ------------------
__global__ __launch_bounds__(256) void quantw_kernel(const float4* __restrict__ w,
                                                     int4* __restrict__ wq,
                                                     const double* __restrict__ sum) {
  float mean = (float)(*sum * (1.0 / (double)WN));
  float den = mean + QEPS;
  int n16 = WN / 16;
  int stride = gridDim.x * blockDim.x;
  for (int i = blockIdx.x * blockDim.x + threadIdx.x; i < n16; i += stride) {
    float4 v0 = w[i * 4 + 0], v1 = w[i * 4 + 1], v2 = w[i * 4 + 2], v3 = w[i * 4 + 3];
    int4 o;
    o.x = pack4div(v0, 1.f, den, -1.f, 1.f);
    o.y = pack4div(v1, 1.f, den, -1.f, 1.f);
    o.z = pack4div(v2, 1.f, den, -1.f, 1.f);
    o.w = pack4div(v3, 1.f, den, -1.f, 1.f);
    wq[i] = o;
  }
}

// -------- combine: relu^2*up, per-row gamma, int8 quant (one block per row) --
__global__ __launch_bounds__(256) void combine_kernel(
    const short* __restrict__ C, const float* __restrict__ scale_x,
    const double* __restrict__ sums, const float* __restrict__ sg,
    const float* __restrict__ su, float* __restrict__ gammaF,
    char* __restrict__ hq) {
  int row = blockIdx.x, t = threadIdx.x;
  float gm = (float)(sums[0] * (1.0 / (double)WN)) * sg[0];
  float um = (float)(sums[1] * (1.0 / (double)WN)) * su[0];
  float sx = scale_x[row];
  float sxg = sx * gm, sxu = sx * um;
  const s16x8* g8 = (const s16x8*)(C + (size_t)row * N1);
  const s16x8* u8 = (const s16x8*)(C + (size_t)row * N1 + ID);
  float hv[6][8];
  float m = 0.f;
#pragma unroll
  for (int k = 0; k < 6; ++k) {
    int c = t + k * 256;
    if (c < ID / 8) {
      s16x8 gi = __builtin_nontemporal_load(&g8[c]);
      s16x8 ui = __builtin_nontemporal_load(&u8[c]);
#pragma unroll
      for (int e = 0; e < 8; ++e) {
        float rg = fmaxf((float)gi[e] * sxg, 0.f);
        hv[k][e] = ((float)ui[e] * sxu) * (rg * rg);
        m = fmaxf(m, fabsf(hv[k][e]));
      }
    }
  }
#pragma unroll
  for (int off = 32; off > 0; off >>= 1) m = fmaxf(m, __shfl_xor(m, off));
  __shared__ float red[4];
  if ((t & 63) == 0) red[t >> 6] = m;
  __syncthreads();
  float gamma = fmaxf(fmaxf(red[0], red[1]), fmaxf(red[2], red[3]));
  if (t == 0) gammaF[row] = gamma;
  float den = gamma + QEPS;
  int2* hr = (int2*)(hq + (size_t)row * ID);
#pragma unroll
  for (int k = 0; k < 6; ++k) {
    int c = t + k * 256;
    if (c < ID / 8) {
      int2 o;
      o.x = pack4div(make_float4(hv[k][0], hv[k][1], hv[k][2], hv[k][3]), 127.f, den, -128.f, 127.f);
      o.y = pack4div(make_float4(hv[k][4], hv[k][5], hv[k][6], hv[k][7]), 127.f, den, -128.f, 127.f);
      hr[c] = o;
    }
  }
}

extern "C" void kernel_launch(void* const* d_in, const int* in_sizes, int n_in,
                              void* d_out, int out_size, void* d_ws, size_t ws_size,
                              hipStream_t stream) {
  (void)in_sizes; (void)n_in; (void)out_size; (void)ws_size;
  const float* x = (const float*)d_in[0];
  const float* w_gate = (const float*)d_in[1];
  const float* w_up = (const float*)d_in[2];
  const float* w_down = (const float*)d_in[3];
  const float* s_gate = (const float*)d_in[4];
  const float* s_up = (const float*)d_in[5];
  const float* s_down = (const float*)d_in[6];
  float* out = (float*)d_out;

  // ws layout (bytes):
  char* p = (char*)d_ws;
  double* sums = (double*)p;                        // 3 doubles
  float* gammaF = (float*)(p + 256);                // 4096 f32
  float* scale_x = (float*)(p + 256 + 16384);       // 4096 f32 -> head ends 33024
  char* xq = p + 33024;                             // 16,777,216
  char* wgq = xq + 16777216UL;                      // 45,088,768 (wuq contiguous after!)
  char* wuq = wgq + (size_t)WN;                     // => [wgq;wuq] = 22016 x 4096 i8
  char* wdq = wuq + (size_t)WN;
  short* C16 = (short*)(wdq + (size_t)WN);          // 180,355,072 (4096 x 22016 i16)
  char* hq = (char*)C16 + 180355072UL;              // 45,088,768  (~378 MB total)

  (void)hipMemsetAsync(p, 0, 256, stream);  // sums

  // interleave per weight so quantw's re-read hits L3 (each weight f32 = 180MB)
  abssum_kernel<<<2048, 256, 0, stream>>>((const float4*)w_gate, WN / 8, sums + 0);
  quantw_kernel<<<2048, 256, 0, stream>>>((const float4*)w_gate, (int4*)wgq, sums + 0);
  abssum_kernel<<<2048, 256, 0, stream>>>((const float4*)w_up, WN / 8, sums + 1);
  quantw_kernel<<<2048, 256, 0, stream>>>((const float4*)w_up, (int4*)wuq, sums + 1);
  abssum_kernel<<<2048, 256, 0, stream>>>((const float4*)w_down, WN / 8, sums + 2);
  quantw_kernel<<<2048, 256, 0, stream>>>((const float4*)w_down, (int4*)wdq, sums + 2);

  quantx_kernel<<<MD, 256, 0, stream>>>(x, xq, scale_x);

  // fused gate|up: M=4096 (16 bm) x N=22016 (86 bn) -> 1376 blocks (= 8*172)
  gemm1_kernel<<<1376, 512, 0, stream>>>(xq, wgq, C16);

  combine_kernel<<<MD, 256, 0, stream>>>(C16, scale_x, sums, s_gate, s_up, gammaF, hq);

  // down: M=4096 x N=4096 -> 256 blocks (= 8*32), K=11008 (172 BK=64 tiles)
  gemm_down_kernel<<<256, 512, 0, stream>>>(hq, wdq, out, gammaF, sums, s_down);
}

// Round 11
// 848.665 us; speedup vs baseline: 2.3492x; 1.3794x over previous
//
#include <hip/hip_runtime.h>
#include <stdint.h>

// BitNet MLP, int8-MFMA, BK=64 4-deep counted-vmcnt pipelined GEMM (r7 base)
// + m201-style 2-phase interleave per K-tile: each 16-MFMA cluster wrapped in
// lgkm0/sched_barrier/setprio with a mid-iter barrier, so next-phase ds_reads
// and stage-issues drain under the previous cluster's in-pipe MFMAs.
// gate|up fused -> C i16 ; combine -> hq i8 ; down GEMM -> f32 out.
// All integer dot products exact; only fp32 scale factors round.
// LDS swizzle lds[row][s16] = g[row][s16 ^ ((row>>1)&3)]: verified 0 conflicts.

typedef int i32x4 __attribute__((ext_vector_type(4)));
typedef short s16x8 __attribute__((ext_vector_type(8)));

#define HD 4096
#define ID 11008
#define MD 4096          // B*S tokens
#define WN 45088768      // 11008*4096 per weight
#define N1 22016         // gate|up fused output width
#define QEPS 1e-5f
#define SQRT7 2.6457513110645907f

#define MFMA_I8(a, b, c) __builtin_amdgcn_mfma_i32_16x16x64_i8(a, b, c, 0, 0, 0)

__device__ __forceinline__ void gload_lds16(const char* g, char* l) {
  __builtin_amdgcn_global_load_lds((const __attribute__((address_space(1))) void*)g,
                                   (__attribute__((address_space(3))) void*)l, 16, 0, 0);
}

// ---- stage a 256row x 64B tile (16KB) with 512 threads, swizzled image -----
// Thread t writes LDS linear (row=t>>2, slot=t&3); source slot ^= (row>>1)&3
// = (t>>3)&3 (second sweep adds 128 rows: (128>>1)&3 == 0, same fn).
__device__ __forceinline__ void stage64(const char* __restrict__ g, int ldk,
                                        char* lds, int w, int l) {
  int t = w * 64 + l;
  int r = t >> 2, sl = (t & 3) ^ ((t >> 3) & 3);
  const char* gp = g + (size_t)r * ldk + (sl << 4);
  char* lp = lds + w * 1024;
#pragma unroll
  for (int i = 0; i < 2; ++i) {
    gload_lds16(gp, lp);
    gp += (size_t)128 * ldk;
    lp += 8192;
  }
}

// ---- 256x256 x K core: 4-deep ring, counted vmcnt, 2-phase interleave ------
// Per iter: wait vmcnt(8) (2 tiles in flight), barrier, then
//   phase0: stage A(t+3) | read bf0-3,af0-3 | lgkm0+SB | prio1 16 MFMA prio0 | BAR
//   phase1: stage B(t+3) | read af4-7       | lgkm0+SB | prio1 16 MFMA prio0
__device__ __forceinline__ void gemm_core(const char* __restrict__ ga,
                                          const char* __restrict__ gb,
                                          int ldk, int nt, char* lds,
                                          i32x4 (&acc)[8][4], int w, int l) {
  const int wr = (w >> 2) * 128, wc = (w & 3) * 64;
  const int lr = l & 15;
  const int sw4 = (((l >> 4) ^ ((l >> 1) & 3)) << 4);
  // prologue: tiles 0,1,2 (A then B per tile; 4 gloads/thread/tile)
#pragma unroll
  for (int pt = 0; pt < 3; ++pt) {
    stage64(ga + (size_t)pt * 64, ldk, lds + pt * 32768, w, l);
    stage64(gb + (size_t)pt * 64, ldk, lds + pt * 32768 + 16384, w, l);
  }
  for (int t = 0; t < nt; ++t) {
    if (t + 2 < nt)      asm volatile("s_waitcnt vmcnt(8)" ::: "memory");
    else if (t + 1 < nt) asm volatile("s_waitcnt vmcnt(4)" ::: "memory");
    else                 asm volatile("s_waitcnt vmcnt(0)" ::: "memory");
    __builtin_amdgcn_s_barrier();
    const char* Ab = lds + (t & 3) * 32768;
    const char* Bb = Ab + 16384;
    char* pre = lds + ((t + 3) & 3) * 32768;  // slot last read at t-1: free
    i32x4 af[8], bf[4];
    // ---------------- phase 0 ----------------
    if (t + 3 < nt) stage64(ga + (size_t)(t + 3) * 64, ldk, pre, w, l);
#pragma unroll
    for (int ni = 0; ni < 4; ++ni)
      bf[ni] = *(const i32x4*)(Bb + (wc + ni * 16 + lr) * 64 + sw4);
#pragma unroll
    for (int mi = 0; mi < 4; ++mi)
      af[mi] = *(const i32x4*)(Ab + (wr + mi * 16 + lr) * 64 + sw4);
    asm volatile("s_waitcnt lgkmcnt(0)" ::: "memory");
    __builtin_amdgcn_sched_barrier(0);
    __builtin_amdgcn_s_setprio(1);
#pragma unroll
    for (int ni = 0; ni < 4; ++ni)
#pragma unroll
      for (int mi = 0; mi < 4; ++mi)
        acc[mi][ni] = MFMA_I8(af[mi], bf[ni], acc[mi][ni]);
    __builtin_amdgcn_s_setprio(0);
    __builtin_amdgcn_s_barrier();
    // ---------------- phase 1 ----------------
    if (t + 3 < nt) stage64(gb + (size_t)(t + 3) * 64, ldk, pre + 16384, w, l);
#pragma unroll
    for (int mi = 0; mi < 4; ++mi)
      af[4 + mi] = *(const i32x4*)(Ab + (wr + 64 + mi * 16 + lr) * 64 + sw4);
    asm volatile("s_waitcnt lgkmcnt(0)" ::: "memory");
    __builtin_amdgcn_sched_barrier(0);
    __builtin_amdgcn_s_setprio(1);
#pragma unroll
    for (int ni = 0; ni < 4; ++ni)
#pragma unroll
      for (int mi = 0; mi < 4; ++mi)
        acc[4 + mi][ni] = MFMA_I8(af[4 + mi], bf[ni], acc[4 + mi][ni]);
    __builtin_amdgcn_s_setprio(0);
  }
}

// ---------------- GEMM1: xq x [wgq;wuq] -> C i16 ----------------------------
__global__ __launch_bounds__(512, 2) void gemm1_kernel(
    const char* __restrict__ A, const char* __restrict__ B, short* __restrict__ C) {
  __shared__ __align__(16) char lds[131072];
  int t = threadIdx.x, w = t >> 6, l = t & 63;
  // bn-major XCD mapping: on-XCD neighbors share B panels (1376 = 8*172)
  int wgid = ((int)blockIdx.x & 7) * 172 + ((int)blockIdx.x >> 3);
  int bm = wgid & 15, bn = wgid >> 4;  // bm in [0,16), bn in [0,86)
  i32x4 acc[8][4] = {};
  gemm_core(A + (size_t)bm * 256 * HD, B + (size_t)bn * 256 * HD, HD, HD / 64,
            lds, acc, w, l);
  int wr = (w >> 2) * 128, wc = (w & 3) * 64, lr = l & 15, lj = (l >> 4) * 4;
#pragma unroll
  for (int mi = 0; mi < 8; ++mi) {
    int row = bm * 256 + wr + mi * 16 + lj;
#pragma unroll
    for (int ni = 0; ni < 4; ++ni) {
      int col = bn * 256 + wc + ni * 16 + lr;
#pragma unroll
      for (int j = 0; j < 4; ++j) {
        int v = acc[mi][ni][j];
        v = v < -32768 ? -32768 : (v > 32767 ? 32767 : v);  // never triggers (|acc|<~2k)
        C[(size_t)(row + j) * N1 + col] = (short)v;
      }
    }
  }
}

// ---------------- GEMM2: hq x wdq, fused scales -> f32 ----------------------
__global__ __launch_bounds__(512, 2) void gemm_down_kernel(
    const char* __restrict__ A, const char* __restrict__ B, float* __restrict__ out,
    const float* __restrict__ gammaF, const double* __restrict__ sums,
    const float* __restrict__ sd) {
  __shared__ __align__(16) char lds[131072];
  int t = threadIdx.x, w = t >> 6, l = t & 63;
  int wgid = ((int)blockIdx.x & 7) * 32 + ((int)blockIdx.x >> 3);  // 256 = 8*32
  int bm = wgid & 15, bn = wgid >> 4;
  i32x4 acc[8][4] = {};
  gemm_core(A + (size_t)bm * 256 * ID, B + (size_t)bn * 256 * ID, ID, ID / 64,
            lds, acc, w, l);
  float wdm = (float)(sums[2] * (1.0 / (double)WN)) * sd[0] * (1.f / 127.f);
  int wr = (w >> 2) * 128, wc = (w & 3) * 64, lr = l & 15, lj = (l >> 4) * 4;
#pragma unroll
  for (int mi = 0; mi < 8; ++mi) {
    int row = bm * 256 + wr + mi * 16 + lj;
    float sa[4];
#pragma unroll
    for (int j = 0; j < 4; ++j) sa[j] = gammaF[row + j] * wdm;
#pragma unroll
    for (int ni = 0; ni < 4; ++ni) {
      int col = bn * 256 + wc + ni * 16 + lr;
#pragma unroll
      for (int j = 0; j < 4; ++j)
        out[(size_t)(row + j) * HD + col] = (float)acc[mi][ni][j] * sa[j];
    }
  }
}

// ---------------- helpers ----------------------------------------------------
__device__ __forceinline__ int pack4div(float4 v, float mul, float den, float lo, float hi) {
  int a = (int)fminf(fmaxf(rintf((v.x * mul) / den), lo), hi);
  int b = (int)fminf(fmaxf(rintf((v.y * mul) / den), lo), hi);
  int c = (int)fminf(fmaxf(rintf((v.z * mul) / den), lo), hi);
  int d = (int)fminf(fmaxf(rintf((v.w * mul) / den), lo), hi);
  return (a & 255) | ((b & 255) << 8) | ((c & 255) << 16) | ((d & 255) << 24);
}

// ---------------- absmean reductions (double atomics) -----------------------
__global__ __launch_bounds__(256) void abssum_kernel(const float4* __restrict__ w,
                                                     int n8, double* __restrict__ out) {
  float s = 0.f;
  int stride = gridDim.x * blockDim.x;
  for (int i = blockIdx.x * blockDim.x + threadIdx.x; i < n8; i += stride) {
    float4 v0 = w[i * 2], v1 = w[i * 2 + 1];
    s += fabsf(v0.x) + fabsf(v0.y) + fabsf(v0.z) + fabsf(v0.w);
    s += fabsf(v1.x) + fabsf(v1.y) + fabsf(v1.z) + fabsf(v1.w);
  }
#pragma unroll
  for (int off = 32; off > 0; off >>= 1) s += __shfl_down(s, off);
  __shared__ float red[4];
  int l = threadIdx.x & 63, wv = threadIdx.x >> 6;
  if (l == 0) red[wv] = s;
  __syncthreads();
  if (threadIdx.x == 0) {
    double tt = (double)red[0] + (double)red[1] + (double)red[2] + (double)red[3];
    atomicAdd(out, tt);
  }
}

// ---------------- per-row beta + int4 quant of x -> i8 ----------------------
__global__ __launch_bounds__(256) void quantx_kernel(const float* __restrict__ x,
                                                     char* __restrict__ xq,
                                                     float* __restrict__ scale_x) {
  int row = blockIdx.x;
  const float4* xr = (const float4*)(x + (size_t)row * HD);
  int t = threadIdx.x;
  float4 v[4];
  float s = 0.f;
#pragma unroll
  for (int k = 0; k < 4; ++k) {
    v[k] = xr[t + k * 256];
    s += fabsf(v[k].x) + fabsf(v[k].y) + fabsf(v[k].z) + fabsf(v[k].w);
  }
#pragma unroll
  for (int off = 32; off > 0; off >>= 1) s += __shfl_down(s, off);
  __shared__ float red[4];
  int l = t & 63, wv = t >> 6;
  if (l == 0) red[wv] = s;
  __syncthreads();
  float beta = (red[0] + red[1] + red[2] + red[3]) * (1.f / (float)HD);
  if (t == 0) scale_x[row] = (beta * SQRT7) / SQRT7;  // ref dequant scale
  float den = beta + QEPS;
  int* qr = (int*)(xq + (size_t)row * HD);
#pragma unroll
  for (int k = 0; k < 4; ++k)
    qr[t + k * 256] = pack4div(v[k], SQRT7, den, -8.f, 7.f);
}

// ---------------- ternary quant of a weight -> i8 {-1,0,1} ------------------
__global__ __launch_bounds__(256) void quantw_kernel(const float4* __restrict__ w,
                                                     int4* __restrict__ wq,
                                                     const double* __restrict__ sum) {
  float mean = (float)(*sum * (1.0 / (double)WN));
  float den = mean + QEPS;
  int n16 = WN / 16;
  int stride = gridDim.x * blockDim.x;
  for (int i = blockIdx.x * blockDim.x + threadIdx.x; i < n16; i += stride) {
    float4 v0 = w[i * 4 + 0], v1 = w[i * 4 + 1], v2 = w[i * 4 + 2], v3 = w[i * 4 + 3];
    int4 o;
    o.x = pack4div(v0, 1.f, den, -1.f, 1.f);
    o.y = pack4div(v1, 1.f, den, -1.f, 1.f);
    o.z = pack4div(v2, 1.f, den, -1.f, 1.f);
    o.w = pack4div(v3, 1.f, den, -1.f, 1.f);
    wq[i] = o;
  }
}

// -------- combine: relu^2*up, per-row gamma, int8 quant (one block per row) --
__global__ __launch_bounds__(256) void combine_kernel(
    const short* __restrict__ C, const float* __restrict__ scale_x,
    const double* __restrict__ sums, const float* __restrict__ sg,
    const float* __restrict__ su, float* __restrict__ gammaF,
    char* __restrict__ hq) {
  int row = blockIdx.x, t = threadIdx.x;
  float gm = (float)(sums[0] * (1.0 / (double)WN)) * sg[0];
  float um = (float)(sums[1] * (1.0 / (double)WN)) * su[0];
  float sx = scale_x[row];
  float sxg = sx * gm, sxu = sx * um;
  const s16x8* g8 = (const s16x8*)(C + (size_t)row * N1);
  const s16x8* u8 = (const s16x8*)(C + (size_t)row * N1 + ID);
  float hv[6][8];
  float m = 0.f;
#pragma unroll
  for (int k = 0; k < 6; ++k) {
    int c = t + k * 256;
    if (c < ID / 8) {
      s16x8 gi = __builtin_nontemporal_load(&g8[c]);
      s16x8 ui = __builtin_nontemporal_load(&u8[c]);
#pragma unroll
      for (int e = 0; e < 8; ++e) {
        float rg = fmaxf((float)gi[e] * sxg, 0.f);
        hv[k][e] = ((float)ui[e] * sxu) * (rg * rg);
        m = fmaxf(m, fabsf(hv[k][e]));
      }
    }
  }
#pragma unroll
  for (int off = 32; off > 0; off >>= 1) m = fmaxf(m, __shfl_xor(m, off));
  __shared__ float red[4];
  if ((t & 63) == 0) red[t >> 6] = m;
  __syncthreads();
  float gamma = fmaxf(fmaxf(red[0], red[1]), fmaxf(red[2], red[3]));
  if (t == 0) gammaF[row] = gamma;
  float den = gamma + QEPS;
  int2* hr = (int2*)(hq + (size_t)row * ID);
#pragma unroll
  for (int k = 0; k < 6; ++k) {
    int c = t + k * 256;
    if (c < ID / 8) {
      int2 o;
      o.x = pack4div(make_float4(hv[k][0], hv[k][1], hv[k][2], hv[k][3]), 127.f, den, -128.f, 127.f);
      o.y = pack4div(make_float4(hv[k][4], hv[k][5], hv[k][6], hv[k][7]), 127.f, den, -128.f, 127.f);
      hr[c] = o;
    }
  }
}

extern "C" void kernel_launch(void* const* d_in, const int* in_sizes, int n_in,
                              void* d_out, int out_size, void* d_ws, size_t ws_size,
                              hipStream_t stream) {
  (void)in_sizes; (void)n_in; (void)out_size; (void)ws_size;
  const float* x = (const float*)d_in[0];
  const float* w_gate = (const float*)d_in[1];
  const float* w_up = (const float*)d_in[2];
  const float* w_down = (const float*)d_in[3];
  const float* s_gate = (const float*)d_in[4];
  const float* s_up = (const float*)d_in[5];
  const float* s_down = (const float*)d_in[6];
  float* out = (float*)d_out;

  // ws layout (bytes):
  char* p = (char*)d_ws;
  double* sums = (double*)p;                        // 3 doubles
  float* gammaF = (float*)(p + 256);                // 4096 f32
  float* scale_x = (float*)(p + 256 + 16384);       // 4096 f32 -> head ends 33024
  char* xq = p + 33024;                             // 16,777,216
  char* wgq = xq + 16777216UL;                      // 45,088,768 (wuq contiguous after!)
  char* wuq = wgq + (size_t)WN;                     // => [wgq;wuq] = 22016 x 4096 i8
  char* wdq = wuq + (size_t)WN;
  short* C16 = (short*)(wdq + (size_t)WN);          // 180,355,072 (4096 x 22016 i16)
  char* hq = (char*)C16 + 180355072UL;              // 45,088,768  (~378 MB total)

  (void)hipMemsetAsync(p, 0, 256, stream);  // sums

  // interleave per weight so quantw's re-read hits L3 (each weight f32 = 180MB)
  abssum_kernel<<<2048, 256, 0, stream>>>((const float4*)w_gate, WN / 8, sums + 0);
  quantw_kernel<<<2048, 256, 0, stream>>>((const float4*)w_gate, (int4*)wgq, sums + 0);
  abssum_kernel<<<2048, 256, 0, stream>>>((const float4*)w_up, WN / 8, sums + 1);
  quantw_kernel<<<2048, 256, 0, stream>>>((const float4*)w_up, (int4*)wuq, sums + 1);
  abssum_kernel<<<2048, 256, 0, stream>>>((const float4*)w_down, WN / 8, sums + 2);
  quantw_kernel<<<2048, 256, 0, stream>>>((const float4*)w_down, (int4*)wdq, sums + 2);

  quantx_kernel<<<MD, 256, 0, stream>>>(x, xq, scale_x);

  // fused gate|up: M=4096 (16 bm) x N=22016 (86 bn) -> 1376 blocks (= 8*172)
  gemm1_kernel<<<1376, 512, 0, stream>>>(xq, wgq, C16);

  combine_kernel<<<MD, 256, 0, stream>>>(C16, scale_x, sums, s_gate, s_up, gammaF, hq);

  // down: M=4096 x N=4096 -> 256 blocks (= 8*32), K=11008 (172 BK=64 tiles)
  gemm_down_kernel<<<256, 512, 0, stream>>>(hq, wdq, out, gammaF, sums, s_down);
}

// Round 12
// 832.787 us; speedup vs baseline: 2.3940x; 1.0191x over previous
//
#include <hip/hip_runtime.h>
#include <stdint.h>

// BitNet MLP, int8-MFMA. GEMM core v4: 4 waves (1/SIMD), per-wave 128x128,
// acc[8][8] FORCED into AGPRs via inline-asm "+a" (512-reg unified budget:
// 256 AGPR acc + ~110 arch VGPR frags/addr -> no spill, unlike r8).
// Rationale (r11 post-mortem): kernel is LDS-pipe bound (96 ds_read_b128/iter
// = ~1150cy > MFMA 330cy wall). 128x128 waves cut reads to 64/iter (-33%).
// 4-deep 32KB LDS ring, counted vmcnt(16/8/0), swizzle verified 0-conflict.
// All integer dot products exact; only fp32 scale factors round.

typedef int i32x4 __attribute__((ext_vector_type(4)));
typedef short s16x8 __attribute__((ext_vector_type(8)));

#define HD 4096
#define ID 11008
#define MD 4096          // B*S tokens
#define WN 45088768      // 11008*4096 per weight
#define N1 22016         // gate|up fused output width
#define QEPS 1e-5f
#define SQRT7 2.6457513110645907f

__device__ __forceinline__ void mfma_a(i32x4& acc, i32x4 a, i32x4 b) {
  asm volatile("v_mfma_i32_16x16x64_i8 %0, %1, %2, %0"
               : "+a"(acc) : "v"(a), "v"(b));
}

__device__ __forceinline__ void gload_lds16(const char* g, char* l) {
  __builtin_amdgcn_global_load_lds((const __attribute__((address_space(1))) void*)g,
                                   (__attribute__((address_space(3))) void*)l, 16, 0, 0);
}

// ---- stage a 256row x 64B half-tile (16KB) with 256 threads, swizzled ------
// Thread t covers LDS bytes t*16 (+4KB per sweep): row=t>>2, slot=t&3.
// Image: lds[row][slot] = g[row][slot ^ ((row>>1)&3)]; source slot =
// (t&3)^((t>>3)&3); sweeps add 64 rows ((64>>1)&3==0, invariant).
// Verified SQ_LDS_BANK_CONFLICT==0 (r6/r7/r11).
__device__ __forceinline__ void stage64q(const char* __restrict__ g, int ldk,
                                         char* lds, int t256) {
  int r = t256 >> 2, sl = (t256 & 3) ^ ((t256 >> 3) & 3);
  const char* gp = g + (size_t)r * ldk + (sl << 4);
  char* lp = lds + t256 * 16;
#pragma unroll
  for (int i = 0; i < 4; ++i) {
    gload_lds16(gp, lp);
    gp += (size_t)64 * ldk;
    lp += 4096;
  }
}

// ---- 256x256 x K core: 4-deep ring, counted vmcnt, 2 n-half phases --------
// Per-thread VMEM issue = 8/iter (4 A + 4 B). Entry-of-iter outstanding:
// stage(t+1)+stage(t+2) = 16 -> vmcnt(16) retires tile t. Tail 8 / 0.
__device__ __forceinline__ void gemm_core(const char* __restrict__ ga,
                                          const char* __restrict__ gb,
                                          int ldk, int nt, char* lds,
                                          i32x4 (&acc)[8][8], int w, int l) {
  const int t256 = w * 64 + l;
  const int wr = (w >> 1) * 128, wc = (w & 1) * 128;
  const int lr = l & 15;
  const int sw4 = (((l >> 4) ^ ((l >> 1) & 3)) << 4);
#pragma unroll
  for (int pt = 0; pt < 3; ++pt) {
    stage64q(ga + (size_t)pt * 64, ldk, lds + pt * 32768, t256);
    stage64q(gb + (size_t)pt * 64, ldk, lds + pt * 32768 + 16384, t256);
  }
  for (int t = 0; t < nt; ++t) {
    if (t + 2 < nt)      asm volatile("s_waitcnt vmcnt(16)" ::: "memory");
    else if (t + 1 < nt) asm volatile("s_waitcnt vmcnt(8)" ::: "memory");
    else                 asm volatile("s_waitcnt vmcnt(0)" ::: "memory");
    __builtin_amdgcn_s_barrier();
    const char* Ab = lds + (t & 3) * 32768;
    const char* Bb = Ab + 16384;
    char* pre = lds + ((t + 3) & 3) * 32768;  // slot last read at t-1 (drained)
    // ---- phase 0: stage A(t+3); read af[0..7], bf[0..3]; 32 MFMA ----
    if (t + 3 < nt) stage64q(ga + (size_t)(t + 3) * 64, ldk, pre, t256);
    i32x4 af[8], bf[8];
#pragma unroll
    for (int i = 0; i < 8; ++i)
      af[i] = *(const i32x4*)(Ab + (wr + i * 16 + lr) * 64 + sw4);
#pragma unroll
    for (int i = 0; i < 4; ++i)
      bf[i] = *(const i32x4*)(Bb + (wc + i * 16 + lr) * 64 + sw4);
#pragma unroll
    for (int n = 0; n < 4; ++n)
#pragma unroll
      for (int m = 0; m < 8; ++m)
        mfma_a(acc[m][n], af[m], bf[n]);
    // ---- phase 1: stage B(t+3); read bf[4..7]; 32 MFMA ----
    if (t + 3 < nt) stage64q(gb + (size_t)(t + 3) * 64, ldk, pre + 16384, t256);
#pragma unroll
    for (int i = 4; i < 8; ++i)
      bf[i] = *(const i32x4*)(Bb + (wc + i * 16 + lr) * 64 + sw4);
#pragma unroll
    for (int n = 4; n < 8; ++n)
#pragma unroll
      for (int m = 0; m < 8; ++m)
        mfma_a(acc[m][n], af[m], bf[n]);
  }
}

// ---------------- GEMM1: xq x [wgq;wuq] -> C i16 ----------------------------
__global__ __launch_bounds__(256, 1) void gemm1_kernel(
    const char* __restrict__ A, const char* __restrict__ B, short* __restrict__ C) {
  __shared__ __align__(16) char lds[131072];
  int t = threadIdx.x, w = t >> 6, l = t & 63;
  // bn-major XCD mapping: on-XCD neighbors share B panels (1376 = 8*172)
  int wgid = ((int)blockIdx.x & 7) * 172 + ((int)blockIdx.x >> 3);
  int bm = wgid & 15, bn = wgid >> 4;  // bm in [0,16), bn in [0,86)
  i32x4 acc[8][8] = {};
  gemm_core(A + (size_t)bm * 256 * HD, B + (size_t)bn * 256 * HD, HD, HD / 64,
            lds, acc, w, l);
  int wr = (w >> 1) * 128, wc = (w & 1) * 128, lr = l & 15, lj = (l >> 4) * 4;
#pragma unroll
  for (int mi = 0; mi < 8; ++mi) {
    int row = bm * 256 + wr + mi * 16 + lj;
#pragma unroll
    for (int ni = 0; ni < 8; ++ni) {
      int col = bn * 256 + wc + ni * 16 + lr;
#pragma unroll
      for (int j = 0; j < 4; ++j) {
        int v = acc[mi][ni][j];
        v = v < -32768 ? -32768 : (v > 32767 ? 32767 : v);  // never triggers (|acc|<~2k)
        C[(size_t)(row + j) * N1 + col] = (short)v;
      }
    }
  }
}

// ---------------- GEMM2: hq x wdq, fused scales -> f32 ----------------------
__global__ __launch_bounds__(256, 1) void gemm_down_kernel(
    const char* __restrict__ A, const char* __restrict__ B, float* __restrict__ out,
    const float* __restrict__ gammaF, const double* __restrict__ sums,
    const float* __restrict__ sd) {
  __shared__ __align__(16) char lds[131072];
  int t = threadIdx.x, w = t >> 6, l = t & 63;
  int wgid = ((int)blockIdx.x & 7) * 32 + ((int)blockIdx.x >> 3);  // 256 = 8*32
  int bm = wgid & 15, bn = wgid >> 4;
  i32x4 acc[8][8] = {};
  gemm_core(A + (size_t)bm * 256 * ID, B + (size_t)bn * 256 * ID, ID, ID / 64,
            lds, acc, w, l);
  float wdm = (float)(sums[2] * (1.0 / (double)WN)) * sd[0] * (1.f / 127.f);
  int wr = (w >> 1) * 128, wc = (w & 1) * 128, lr = l & 15, lj = (l >> 4) * 4;
#pragma unroll
  for (int mi = 0; mi < 8; ++mi) {
    int row = bm * 256 + wr + mi * 16 + lj;
    float sa[4];
#pragma unroll
    for (int j = 0; j < 4; ++j) sa[j] = gammaF[row + j] * wdm;
#pragma unroll
    for (int ni = 0; ni < 8; ++ni) {
      int col = bn * 256 + wc + ni * 16 + lr;
#pragma unroll
      for (int j = 0; j < 4; ++j)
        out[(size_t)(row + j) * HD + col] = (float)acc[mi][ni][j] * sa[j];
    }
  }
}

// ---------------- helpers ----------------------------------------------------
__device__ __forceinline__ int pack4div(float4 v, float mul, float den, float lo, float hi) {
  int a = (int)fminf(fmaxf(rintf((v.x * mul) / den), lo), hi);
  int b = (int)fminf(fmaxf(rintf((v.y * mul) / den), lo), hi);
  int c = (int)fminf(fmaxf(rintf((v.z * mul) / den), lo), hi);
  int d = (int)fminf(fmaxf(rintf((v.w * mul) / den), lo), hi);
  return (a & 255) | ((b & 255) << 8) | ((c & 255) << 16) | ((d & 255) << 24);
}

// ---------------- absmean reductions (double atomics) -----------------------
__global__ __launch_bounds__(256) void abssum_kernel(const float4* __restrict__ w,
                                                     int n8, double* __restrict__ out) {
  float s = 0.f;
  int stride = gridDim.x * blockDim.x;
  for (int i = blockIdx.x * blockDim.x + threadIdx.x; i < n8; i += stride) {
    float4 v0 = w[i * 2], v1 = w[i * 2 + 1];
    s += fabsf(v0.x) + fabsf(v0.y) + fabsf(v0.z) + fabsf(v0.w);
    s += fabsf(v1.x) + fabsf(v1.y) + fabsf(v1.z) + fabsf(v1.w);
  }
#pragma unroll
  for (int off = 32; off > 0; off >>= 1) s += __shfl_down(s, off);
  __shared__ float red[4];
  int l = threadIdx.x & 63, wv = threadIdx.x >> 6;
  if (l == 0) red[wv] = s;
  __syncthreads();
  if (threadIdx.x == 0) {
    double tt = (double)red[0] + (double)red[1] + (double)red[2] + (double)red[3];
    atomicAdd(out, tt);
  }
}

// ---------------- per-row beta + int4 quant of x -> i8 ----------------------
__global__ __launch_bounds__(256) void quantx_kernel(const float* __restrict__ x,
                                                     char* __restrict__ xq,
                                                     float* __restrict__ scale_x) {
  int row = blockIdx.x;
  const float4* xr = (const float4*)(x + (size_t)row * HD);
  int t = threadIdx.x;
  float4 v[4];
  float s = 0.f;
#pragma unroll
  for (int k = 0; k < 4; ++k) {
    v[k] = xr[t + k * 256];
    s += fabsf(v[k].x) + fabsf(v[k].y) + fabsf(v[k].z) + fabsf(v[k].w);
  }
#pragma unroll
  for (int off = 32; off > 0; off >>= 1) s += __shfl_down(s, off);
  __shared__ float red[4];
  int l = t & 63, wv = t >> 6;
  if (l == 0) red[wv] = s;
  __syncthreads();
  float beta = (red[0] + red[1] + red[2] + red[3]) * (1.f / (float)HD);
  if (t == 0) scale_x[row] = (beta * SQRT7) / SQRT7;  // ref dequant scale
  float den = beta + QEPS;
  int* qr = (int*)(xq + (size_t)row * HD);
#pragma unroll
  for (int k = 0; k < 4; ++k)
    qr[t + k * 256] = pack4div(v[k], SQRT7, den, -8.f, 7.f);
}

// ---------------- ternary quant of a weight -> i8 {-1,0,1} ------------------
__global__ __launch_bounds__(256) void quantw_kernel(const float4* __restrict__ w,
                                                     int4* __restrict__ wq,
                                                     const double* __restrict__ sum) {
  float mean = (float)(*sum * (1.0 / (double)WN));
  float den = mean + QEPS;
  int n16 = WN / 16;
  int stride = gridDim.x * blockDim.x;
  for (int i = blockIdx.x * blockDim.x + threadIdx.x; i < n16; i += stride) {
    float4 v0 = w[i * 4 + 0], v1 = w[i * 4 + 1], v2 = w[i * 4 + 2], v3 = w[i * 4 + 3];
    int4 o;
    o.x = pack4div(v0, 1.f, den, -1.f, 1.f);
    o.y = pack4div(v1, 1.f, den, -1.f, 1.f);
    o.z = pack4div(v2, 1.f, den, -1.f, 1.f);
    o.w = pack4div(v3, 1.f, den, -1.f, 1.f);
    wq[i] = o;
  }
}

// -------- combine: relu^2*up, per-row gamma, int8 quant (one block per row) --
__global__ __launch_bounds__(256) void combine_kernel(
    const short* __restrict__ C, const float* __restrict__ scale_x,
    const double* __restrict__ sums, const float* __restrict__ sg,
    const float* __restrict__ su, float* __restrict__ gammaF,
    char* __restrict__ hq) {
  int row = blockIdx.x, t = threadIdx.x;
  float gm = (float)(sums[0] * (1.0 / (double)WN)) * sg[0];
  float um = (float)(sums[1] * (1.0 / (double)WN)) * su[0];
  float sx = scale_x[row];
  float sxg = sx * gm, sxu = sx * um;
  const s16x8* g8 = (const s16x8*)(C + (size_t)row * N1);
  const s16x8* u8 = (const s16x8*)(C + (size_t)row * N1 + ID);
  float hv[6][8];
  float m = 0.f;
#pragma unroll
  for (int k = 0; k < 6; ++k) {
    int c = t + k * 256;
    if (c < ID / 8) {
      s16x8 gi = __builtin_nontemporal_load(&g8[c]);
      s16x8 ui = __builtin_nontemporal_load(&u8[c]);
#pragma unroll
      for (int e = 0; e < 8; ++e) {
        float rg = fmaxf((float)gi[e] * sxg, 0.f);
        hv[k][e] = ((float)ui[e] * sxu) * (rg * rg);
        m = fmaxf(m, fabsf(hv[k][e]));
      }
    }
  }
#pragma unroll
  for (int off = 32; off > 0; off >>= 1) m = fmaxf(m, __shfl_xor(m, off));
  __shared__ float red[4];
  if ((t & 63) == 0) red[t >> 6] = m;
  __syncthreads();
  float gamma = fmaxf(fmaxf(red[0], red[1]), fmaxf(red[2], red[3]));
  if (t == 0) gammaF[row] = gamma;
  float den = gamma + QEPS;
  int2* hr = (int2*)(hq + (size_t)row * ID);
#pragma unroll
  for (int k = 0; k < 6; ++k) {
    int c = t + k * 256;
    if (c < ID / 8) {
      int2 o;
      o.x = pack4div(make_float4(hv[k][0], hv[k][1], hv[k][2], hv[k][3]), 127.f, den, -128.f, 127.f);
      o.y = pack4div(make_float4(hv[k][4], hv[k][5], hv[k][6], hv[k][7]), 127.f, den, -128.f, 127.f);
      hr[c] = o;
    }
  }
}

extern "C" void kernel_launch(void* const* d_in, const int* in_sizes, int n_in,
                              void* d_out, int out_size, void* d_ws, size_t ws_size,
                              hipStream_t stream) {
  (void)in_sizes; (void)n_in; (void)out_size; (void)ws_size;
  const float* x = (const float*)d_in[0];
  const float* w_gate = (const float*)d_in[1];
  const float* w_up = (const float*)d_in[2];
  const float* w_down = (const float*)d_in[3];
  const float* s_gate = (const float*)d_in[4];
  const float* s_up = (const float*)d_in[5];
  const float* s_down = (const float*)d_in[6];
  float* out = (float*)d_out;

  // ws layout (bytes):
  char* p = (char*)d_ws;
  double* sums = (double*)p;                        // 3 doubles
  float* gammaF = (float*)(p + 256);                // 4096 f32
  float* scale_x = (float*)(p + 256 + 16384);       // 4096 f32 -> head ends 33024
  char* xq = p + 33024;                             // 16,777,216
  char* wgq = xq + 16777216UL;                      // 45,088,768 (wuq contiguous after!)
  char* wuq = wgq + (size_t)WN;                     // => [wgq;wuq] = 22016 x 4096 i8
  char* wdq = wuq + (size_t)WN;
  short* C16 = (short*)(wdq + (size_t)WN);          // 180,355,072 (4096 x 22016 i16)
  char* hq = (char*)C16 + 180355072UL;              // 45,088,768  (~378 MB total)

  (void)hipMemsetAsync(p, 0, 256, stream);  // sums

  // interleave per weight so quantw's re-read hits L3 (each weight f32 = 180MB)
  abssum_kernel<<<2048, 256, 0, stream>>>((const float4*)w_gate, WN / 8, sums + 0);
  quantw_kernel<<<2048, 256, 0, stream>>>((const float4*)w_gate, (int4*)wgq, sums + 0);
  abssum_kernel<<<2048, 256, 0, stream>>>((const float4*)w_up, WN / 8, sums + 1);
  quantw_kernel<<<2048, 256, 0, stream>>>((const float4*)w_up, (int4*)wuq, sums + 1);
  abssum_kernel<<<2048, 256, 0, stream>>>((const float4*)w_down, WN / 8, sums + 2);
  quantw_kernel<<<2048, 256, 0, stream>>>((const float4*)w_down, (int4*)wdq, sums + 2);

  quantx_kernel<<<MD, 256, 0, stream>>>(x, xq, scale_x);

  // fused gate|up: M=4096 (16 bm) x N=22016 (86 bn) -> 1376 blocks (= 8*172)
  gemm1_kernel<<<1376, 256, 0, stream>>>(xq, wgq, C16);

  combine_kernel<<<MD, 256, 0, stream>>>(C16, scale_x, sums, s_gate, s_up, gammaF, hq);

  // down: M=4096 x N=4096 -> 256 blocks (= 8*32), K=11008 (172 BK=64 tiles)
  gemm_down_kernel<<<256, 256, 0, stream>>>(hq, wdq, out, gammaF, sums, s_down);
}